// Round 16
// baseline (1307.540 us; speedup 1.0000x reference)
//
#include <hip/hip_runtime.h>

typedef __attribute__((ext_vector_type(8))) short bf16x8;
typedef __attribute__((ext_vector_type(4))) float f32x4;
typedef __attribute__((ext_vector_type(2))) _Float16 f16x2;

#define MFMA(a, b, c) __builtin_amdgcn_mfma_f32_16x16x32_bf16((a), (b), (c), 0, 0, 0)

__device__ __forceinline__ unsigned short f2bf(float f) {
    unsigned int u = __builtin_bit_cast(unsigned int, f);
    return (unsigned short)((u + 0x7FFFu + ((u >> 16) & 1u)) >> 16);  // RNE
}
__device__ __forceinline__ float softplusf(float v) {
    return __logf(1.f + __expf(v));
}

// Prepack to bf16 in ws: dyn h-weights [256 u][256 k] at ws[0..65535],
// W_x [512 out][64 k] at ws[65536..98303].
__global__ __launch_bounds__(256) void prepack_kernel(const float* __restrict__ W_gd,
                                                      unsigned short* __restrict__ ws) {
    int i = blockIdx.x * 256 + threadIdx.x;                     // 0..65535
    ws[i] = f2bf(W_gd[(256 + (i >> 8)) * 320 + 64 + (i & 255)]);
    if (i < 32768) ws[65536 + i] = f2bf(W_gd[(i >> 6) * 320 + (i & 63)]);
}

// B=512, S=128, I=64, H=256, C=10
// 256 blocks (2 batch rows) x 1024 threads (16 waves), 1 block/CU.
// = R15 + (a) raw s_barrier (lgkmcnt(0) only -> vmcnt NOT drained at stage
// barriers, per the verified m201 pattern), (b) 2-frag cross-stage dyn
// prefetch P0/P1 (8 regs; refilled mid-sweep -> ~400cy lead over next
// stage's first consumes; R14 showed 28-reg deep prefetch spills), (c)
// v_cvt_pk_bf16_f32 for the h write (saves ~8 VALU/stage).
// Partition (fixed): regs = gate 32; LDS = tau 128K XOR-swz + dyn chunk0 16K;
// L2 stream = dyn chunks 1-7 112KB/CU/stage.
__global__ __launch_bounds__(1024, 1)
void ltc_kernel(
    const float* __restrict__ x, const float* __restrict__ W_gd,
    const float* __restrict__ b_gd, const float* __restrict__ W_tau,
    const float* __restrict__ b_tau, const float* __restrict__ gleak,
    const float* __restrict__ cm, const float* __restrict__ W_fc,
    const float* __restrict__ b_fc, const unsigned short* __restrict__ ws,
    float* __restrict__ out)
{
    const int tid  = threadIdx.x;
    const int lane = tid & 63;
    const int wv   = tid >> 6;          // wave 0..15, owns units 16*wv..16*wv+15
    const int c16  = lane & 15;
    const int kg8  = (lane >> 4) * 8;
    const int row0 = blockIdx.x * 2;

    __shared__ __align__(16) unsigned short tauL[65536];       // tau, 4-bit XOR swizzle (128 KB)
    __shared__ __align__(16) unsigned short dynL[8192];        // dyn K-chunk0 (16 KB)
    __shared__ __align__(16) unsigned short abuf[2][2][264];   // ping-pong h_eff [p][row][u]
    __shared__ __align__(16) unsigned short xbuf[2][2][72];    // x_t, ts-parity ping-pong
    __shared__ __align__(8)  float tcL[512];                   // {b_tau, cden}
    __shared__ float bgdL[512];
    __shared__ float hout[2][257];

    // ---- LDS fills (one-time) ----
    for (int i = tid; i < 65536; i += 1024) {
        int uu = i >> 8, k = i & 255;
        tauL[uu * 256 + (k ^ ((uu & 15) << 3))] = f2bf(W_tau[i]);
    }
    for (int i = tid; i < 8192; i += 1024) {
        int uu = i >> 5, k = i & 31;
        dynL[uu * 32 + (k ^ ((uu & 3) << 3))] = f2bf(W_gd[(256 + uu) * 320 + 64 + k]);
    }
    for (int i = tid; i < 2 * 2 * 264; i += 1024) ((unsigned short*)abuf)[i] = 0;
    if (tid < 256) {
        tcL[2 * tid]     = b_tau[tid];
        tcL[2 * tid + 1] = softplusf(cm[tid]) + softplusf(gleak[tid]) + 1e-6f;
    }
    if (tid < 512) bgdL[tid] = b_gd[tid];
    if (tid < 128) {                                           // stage x for ts=0
        int r = tid >> 6, i = tid & 63;
        xbuf[0][r][i] = f2bf(x[(row0 + r) * 128 * 64 + i]);
    }

    const int u = wv * 16 + c16;                 // this lane's hidden unit
    const int tswz = c16 << 3;                   // tau swizzle key (u&15 == c16)
    const unsigned short* tb = tauL + u * 256;
    const bf16x8* d0p = (const bf16x8*)(dynL + u * 32 + (kg8 ^ ((c16 & 3) << 3)));
    const int vOffD = u * 256 + kg8;             // dyn stream base (ws elements)
    const int vOffX = 65536 + u * 64 + kg8;      // W_x gate row; dyn row at +16384

    // ---- gate weights into registers: 8 frags = 32 VGPR ----
    bf16x8 Wg[8];
    {
        const float* src = W_gd + u * 320 + 64;
        #pragma unroll
        for (int s = 0; s < 8; ++s) {
            const float4* p = (const float4*)(src + s * 32 + kg8);
            float4 a = p[0], b = p[1];
            bf16x8 v;
            v[0] = (short)f2bf(a.x); v[1] = (short)f2bf(a.y);
            v[2] = (short)f2bf(a.z); v[3] = (short)f2bf(a.w);
            v[4] = (short)f2bf(b.x); v[5] = (short)f2bf(b.y);
            v[6] = (short)f2bf(b.z); v[7] = (short)f2bf(b.w);
            Wg[s] = v;
        }
    }

    const int rsel = (c16 < 2) ? c16 : 0;        // pad rows broadcast row 0 (never consumed)
    const unsigned short* aptrP0 = &abuf[0][rsel][kg8];
    const unsigned short* aptrP1 = &abuf[1][rsel][kg8];
    const unsigned short* xptrP0 = &xbuf[0][rsel][kg8];
    const unsigned short* xptrP1 = &xbuf[1][rsel][kg8];

    float hv[2] = {0.f, 0.f};
    f16x2 zh; zh[0] = (_Float16)0.f; zh[1] = (_Float16)0.f;
    f16x2 kk1 = zh, kk2 = zh, kk3 = zh;

    // cross-stage dyn prefetch: frags 0,1 (consumed at s=1,2 of every stage)
    bf16x8 P0 = *(const bf16x8*)(ws + vOffD + 32);
    bf16x8 P1 = *(const bf16x8*)(ws + vOffD + 64);

    __syncthreads();
    const float2 tc = *(const float2*)(tcL + 2 * u);
    const float bg = bgdL[u], bd = bgdL[256 + u];

    #pragma unroll 1
    for (int ts = 0; ts < 128; ++ts) {
        // ---- x-part GEMM from this ts's parity buffer (staged last ts) ----
        const unsigned short* xptr = (ts & 1) ? xptrP1 : xptrP0;
        f32x4 gx0 = {0,0,0,0}, gx1 = {0,0,0,0};
        #pragma unroll
        for (int s = 0; s < 2; ++s) {
            bf16x8 ax = *(const bf16x8*)(xptr + s * 32);
            gx0 = MFMA(ax, *(const bf16x8*)(ws + vOffX + s * 32), gx0);
            gx1 = MFMA(ax, *(const bf16x8*)(ws + vOffX + 16384 + s * 32), gx1);
        }
        f16x2 gdxG, gdxD;
        gdxG[0] = (_Float16)(gx0[0] + bg); gdxG[1] = (_Float16)(gx0[1] + bg);
        gdxD[0] = (_Float16)(gx1[0] + bd); gdxD[1] = (_Float16)(gx1[1] + bd);

        // ---- stage ts+1's x into the opposite parity buffer ----
        if (tid < 128) {
            int r = tid >> 6, i = tid & 63;
            int tn = (ts < 127) ? ts + 1 : 127;
            xbuf[(ts + 1) & 1][r][i] = f2bf(x[((row0 + r) * 128 + tn) * 64 + i]);
        }

        // ---- 4 RK stages; read abuf[stg&1], write abuf[1^(stg&1)], 1 barrier ----
        #pragma unroll
        for (int stg = 0; stg < 4; ++stg) {
            const int p = stg & 1;
            const unsigned short* aptr = p ? aptrP1 : aptrP0;
            unsigned short (*wbuf)[264] = abuf[p ^ 1];

            // this stage's remaining stream frags 2..6 (consumed s=3..7)
            bf16x8 Bq[5];
            #pragma unroll
            for (int i = 0; i < 5; ++i)
                Bq[i] = *(const bf16x8*)(ws + vOffD + (i + 3) * 32);

            f32x4 T = {0,0,0,0}, G = {0,0,0,0}, D = {0,0,0,0};
            {
                bf16x8 A = *(const bf16x8*)(aptr);
                T = MFMA(A, *(const bf16x8*)(tb + (kg8 ^ tswz)), T);
                G = MFMA(A, Wg[0], G);
                D = MFMA(A, *d0p, D);
            }
            {   // s=1,2 consume the cross-stage prefetch (no L2 stall)
                bf16x8 A = *(const bf16x8*)(aptr + 32);
                T = MFMA(A, *(const bf16x8*)(tb + ((32 + kg8) ^ tswz)), T);
                G = MFMA(A, Wg[1], G);
                D = MFMA(A, P0, D);
            }
            {
                bf16x8 A = *(const bf16x8*)(aptr + 64);
                T = MFMA(A, *(const bf16x8*)(tb + ((64 + kg8) ^ tswz)), T);
                G = MFMA(A, Wg[2], G);
                D = MFMA(A, P1, D);
            }
            // refill P0,P1 for the NEXT stage (same addresses every stage);
            // they stay in flight across ELEM + raw barrier (vmcnt not drained)
            P0 = *(const bf16x8*)(ws + vOffD + 32);
            P1 = *(const bf16x8*)(ws + vOffD + 64);
            #pragma unroll
            for (int s = 3; s < 8; ++s) {
                bf16x8 A = *(const bf16x8*)(aptr + s * 32);
                T = MFMA(A, *(const bf16x8*)(tb + ((s * 32 + kg8) ^ tswz)), T);
                G = MFMA(A, Wg[s], G);
                D = MFMA(A, Bq[s - 3], D);
            }

            float den[2];
            den[0] = softplusf(T[0] + tc.x) + tc.y;
            den[1] = softplusf(T[1] + tc.x) + tc.y;
            float en[2];
            #pragma unroll
            for (int r = 0; r < 2; ++r) {
                float gate = G[r] + (float)gdxG[r];
                float dyn  = D[r] + (float)gdxD[r];
                float sig = __fdividef(1.f, 1.f + __expf(-gate));
                float th  = 1.f - __fdividef(2.f, __expf(2.f * dyn) + 1.f);
                float k1v = (float)kk1[r], k2v = (float)kk2[r], k3v = (float)kk3[r];
                float h0 = hv[r];
                float ec;
                if      (stg == 0) ec = h0;
                else if (stg == 1) ec = h0 + k1v * (1.f / 3.f);
                else if (stg == 2) ec = h0 - k1v * (1.f / 3.f) + k2v;
                else               ec = h0 + k1v - k2v + k3v;
                float kv = __fdividef(sig * th - ec, den[r]);
                if (stg == 0)      { kk1[r] = (_Float16)kv; en[r] = h0 + kv * (1.f / 3.f); }
                else if (stg == 1) { kk2[r] = (_Float16)kv; en[r] = h0 - k1v * (1.f / 3.f) + kv; }
                else if (stg == 2) { kk3[r] = (_Float16)kv; en[r] = h0 + k1v - k2v + kv; }
                else               { en[r] = h0 + 0.125f * (k1v + 3.f * (k2v + k3v) + kv); hv[r] = en[r]; }
            }
            unsigned int pk;   // RNE pack of both h rows in one op
            asm("v_cvt_pk_bf16_f32 %0, %1, %2" : "=v"(pk) : "v"(en[0]), "v"(en[1]));
            if (lane < 16) {
                wbuf[0][u] = (unsigned short)pk;
                wbuf[1][u] = (unsigned short)(pk >> 16);
            }

            // raw barrier: drain LDS ops for cross-wave visibility of wbuf,
            // but do NOT drain vmcnt -> P0/P1 stay in flight (m201 pattern)
            asm volatile("s_waitcnt lgkmcnt(0)" ::: "memory");
            __builtin_amdgcn_s_barrier();
        }
    }

    // ---- epilogue: out = h @ W_fc^T + b_fc ----
    if (lane < 16) { hout[0][u] = hv[0]; hout[1][u] = hv[1]; }
    __syncthreads();
    if (tid < 20) {
        int r = tid / 10, c = tid % 10;
        float acc = b_fc[c];
        for (int k = 0; k < 256; ++k) acc = fmaf(hout[r][k], W_fc[c * 256 + k], acc);
        out[(row0 + r) * 10 + c] = acc;
    }
}

extern "C" void kernel_launch(void* const* d_in, const int* in_sizes, int n_in,
                              void* d_out, int out_size, void* d_ws, size_t ws_size,
                              hipStream_t stream) {
    (void)in_sizes; (void)n_in; (void)out_size; (void)ws_size;
    unsigned short* ws16 = (unsigned short*)d_ws;
    prepack_kernel<<<256, 256, 0, stream>>>((const float*)d_in[1], ws16);
    ltc_kernel<<<256, 1024, 0, stream>>>(
        (const float*)d_in[0], (const float*)d_in[1], (const float*)d_in[2],
        (const float*)d_in[3], (const float*)d_in[4], (const float*)d_in[5],
        (const float*)d_in[6], (const float*)d_in[7], (const float*)d_in[8],
        ws16, (float*)d_out);
}

// Round 17
// 911.916 us; speedup vs baseline: 1.4338x; 1.4338x over previous
//
#include <hip/hip_runtime.h>

typedef __attribute__((ext_vector_type(8))) short bf16x8;
typedef __attribute__((ext_vector_type(4))) float f32x4;
typedef __attribute__((ext_vector_type(2))) _Float16 f16x2;

#define MFMA(a, b, c) __builtin_amdgcn_mfma_f32_16x16x32_bf16((a), (b), (c), 0, 0, 0)

__device__ __forceinline__ unsigned short f2bf(float f) {
    unsigned int u = __builtin_bit_cast(unsigned int, f);
    return (unsigned short)((u + 0x7FFFu + ((u >> 16) & 1u)) >> 16);  // RNE
}
__device__ __forceinline__ float softplusf(float v) {
    return __logf(1.f + __expf(v));
}

// Prepack to bf16 in ws: dyn h-weights [256 u][256 k] at ws[0..65535],
// W_x [512 out][64 k] at ws[65536..98303].
__global__ __launch_bounds__(256) void prepack_kernel(const float* __restrict__ W_gd,
                                                      unsigned short* __restrict__ ws) {
    int i = blockIdx.x * 256 + threadIdx.x;                     // 0..65535
    ws[i] = f2bf(W_gd[(256 + (i >> 8)) * 320 + 64 + (i & 255)]);
    if (i < 32768) ws[65536 + i] = f2bf(W_gd[(i >> 6) * 320 + (i & 63)]);
}

// B=512, S=128, I=64, H=256, C=10
// 256 blocks (2 batch rows) x 1024 threads (16 waves), 1 block/CU.
// == R12 verbatim (911us, session best) ==
// Register law (R1-R11): regs/lane = 65536/blockDim = 64, no attribute or
// AGPR path moves it. Partition at the 64-reg optimum: gate weights in regs
// (32); tau full (128K, 4-bit XOR swizzle) + dyn chunk0 (16K) in LDS; dyn
// chunks 1-7 streamed from L2 (112KB/CU/stage), loads compiler-sunk next to
// consumes (any longer liveness spills: R14 703MB, R16 278MB HBM).
// Stage floor: LDS-pipe ~2170cy + L2 ~2050cy, measured 4330cy (imperfect
// overlap, register-blocked). 16 waves = 4 waves/SIMD TLP.
__global__ __launch_bounds__(1024, 1)
void ltc_kernel(
    const float* __restrict__ x, const float* __restrict__ W_gd,
    const float* __restrict__ b_gd, const float* __restrict__ W_tau,
    const float* __restrict__ b_tau, const float* __restrict__ gleak,
    const float* __restrict__ cm, const float* __restrict__ W_fc,
    const float* __restrict__ b_fc, const unsigned short* __restrict__ ws,
    float* __restrict__ out)
{
    const int tid  = threadIdx.x;
    const int lane = tid & 63;
    const int wv   = tid >> 6;          // wave 0..15, owns units 16*wv..16*wv+15
    const int c16  = lane & 15;
    const int kg   = lane >> 4;
    const int kg8  = kg * 8;
    const int row0 = blockIdx.x * 2;

    __shared__ __align__(16) unsigned short tauL[65536];       // tau, 4-bit XOR swizzle (128 KB)
    __shared__ __align__(16) unsigned short dynL[8192];        // dyn K-chunk0, all 256 units (16 KB)
    __shared__ __align__(16) unsigned short abuf[2][2][264];   // ping-pong h_eff [p][row][u]
    __shared__ __align__(16) unsigned short xbuf[2][72];
    __shared__ __align__(8)  float tcL[512];                   // {b_tau, cden}
    __shared__ float bgdL[512];
    __shared__ float hout[2][257];

    // ---- LDS fills ----
    for (int i = tid; i < 65536; i += 1024) {
        int uu = i >> 8, k = i & 255;
        tauL[uu * 256 + (k ^ ((uu & 15) << 3))] = f2bf(W_tau[i]);
    }
    for (int i = tid; i < 8192; i += 1024) {
        int uu = i >> 5, k = i & 31;
        dynL[uu * 32 + (k ^ ((uu & 3) << 3))] = f2bf(W_gd[(256 + uu) * 320 + 64 + k]);
    }
    for (int i = tid; i < 2 * 2 * 264; i += 1024) ((unsigned short*)abuf)[i] = 0;
    if (tid < 256) {
        tcL[2 * tid]     = b_tau[tid];
        tcL[2 * tid + 1] = softplusf(cm[tid]) + softplusf(gleak[tid]) + 1e-6f;
    }
    if (tid < 512) bgdL[tid] = b_gd[tid];

    const int u = wv * 16 + c16;                 // this lane's hidden unit
    const int tswz = c16 << 3;                   // tau swizzle key (u&15 == c16)
    const unsigned short* tb = tauL + u * 256;
    const bf16x8* d0p = (const bf16x8*)(dynL + u * 32 + (kg8 ^ ((c16 & 3) << 3)));
    const int vOffD = u * 256 + kg8;             // dyn stream base (ws elements)
    const int vOffX = 65536 + u * 64 + kg8;      // W_x gate row; dyn row at +16384

    // ---- gate weights into registers: 8 frags = 32 VGPR ----
    bf16x8 Wg[8];
    {
        const float* src = W_gd + u * 320 + 64;
        #pragma unroll
        for (int s = 0; s < 8; ++s) {
            const float4* p = (const float4*)(src + s * 32 + kg8);
            float4 a = p[0], b = p[1];
            bf16x8 v;
            v[0] = (short)f2bf(a.x); v[1] = (short)f2bf(a.y);
            v[2] = (short)f2bf(a.z); v[3] = (short)f2bf(a.w);
            v[4] = (short)f2bf(b.x); v[5] = (short)f2bf(b.y);
            v[6] = (short)f2bf(b.z); v[7] = (short)f2bf(b.w);
            Wg[s] = v;
        }
    }

    const int rsel = (c16 < 2) ? c16 : 0;        // pad rows broadcast row 0 (never consumed)
    const unsigned short* aptrP0 = &abuf[0][rsel][kg8];
    const unsigned short* aptrP1 = &abuf[1][rsel][kg8];
    const unsigned short* xptr   = &xbuf[rsel][kg8];

    // RK state: lane<16 holds rows 0,1 (regs 0,1) of unit u
    float hv[2] = {0.f, 0.f};
    f16x2 zh; zh[0] = (_Float16)0.f; zh[1] = (_Float16)0.f;
    f16x2 kk1 = zh, kk2 = zh, kk3 = zh;

    __syncthreads();

    #pragma unroll 1
    for (int ts = 0; ts < 128; ++ts) {
        if (tid < 128) {
            int r = tid >> 6, i = tid & 63;
            xbuf[r][i] = f2bf(x[((row0 + r) * 128 + ts) * 64 + i]);
        }
        __syncthreads();

        // ---- x-part GEMM (once per step): gate-x and dyn-x for unit u ----
        f32x4 gx0 = {0,0,0,0}, gx1 = {0,0,0,0};
        #pragma unroll
        for (int s = 0; s < 2; ++s) {
            bf16x8 ax = *(const bf16x8*)(xptr + s * 32);
            gx0 = MFMA(ax, *(const bf16x8*)(ws + vOffX + s * 32), gx0);
            gx1 = MFMA(ax, *(const bf16x8*)(ws + vOffX + 16384 + s * 32), gx1);
        }
        f16x2 gdxG, gdxD;
        {
            float bg = bgdL[u], bd = bgdL[256 + u];
            gdxG[0] = (_Float16)(gx0[0] + bg); gdxG[1] = (_Float16)(gx0[1] + bg);
            gdxD[0] = (_Float16)(gx1[0] + bd); gdxD[1] = (_Float16)(gx1[1] + bd);
        }

        // ---- 4 RK stages; read abuf[stg&1], write abuf[1^(stg&1)], 1 barrier ----
        #pragma unroll
        for (int stg = 0; stg < 4; ++stg) {
            const int p = stg & 1;
            const unsigned short* aptr = p ? aptrP1 : aptrP0;
            unsigned short (*wbuf)[264] = abuf[p ^ 1];

            // dyn stream frags for s=1..7 (straight-line; compiler schedules issue)
            bf16x8 Bq[7];
            #pragma unroll
            for (int i = 0; i < 7; ++i)
                Bq[i] = *(const bf16x8*)(ws + vOffD + (i + 1) * 32);

            f32x4 T = {0,0,0,0}, G = {0,0,0,0}, D = {0,0,0,0};
            {
                bf16x8 A = *(const bf16x8*)(aptr);
                T = MFMA(A, *(const bf16x8*)(tb + (kg8 ^ tswz)), T);
                G = MFMA(A, Wg[0], G);
                D = MFMA(A, *d0p, D);
            }
            #pragma unroll
            for (int s = 1; s < 8; ++s) {
                bf16x8 A = *(const bf16x8*)(aptr + s * 32);
                T = MFMA(A, *(const bf16x8*)(tb + ((s * 32 + kg8) ^ tswz)), T);
                G = MFMA(A, Wg[s], G);
                D = MFMA(A, Bq[s - 1], D);
            }

            float2 tc = *(const float2*)(tcL + 2 * u);
            float den0 = softplusf(T[0] + tc.x) + tc.y;
            float den1 = softplusf(T[1] + tc.x) + tc.y;
            float den[2] = { den0, den1 };
            float en[2];
            #pragma unroll
            for (int r = 0; r < 2; ++r) {
                float gate = G[r] + (float)gdxG[r];
                float dyn  = D[r] + (float)gdxD[r];
                float sig = __fdividef(1.f, 1.f + __expf(-gate));
                float th  = 1.f - __fdividef(2.f, __expf(2.f * dyn) + 1.f);
                float k1v = (float)kk1[r], k2v = (float)kk2[r], k3v = (float)kk3[r];
                float h0 = hv[r];
                float ec;
                if      (stg == 0) ec = h0;
                else if (stg == 1) ec = h0 + k1v * (1.f / 3.f);
                else if (stg == 2) ec = h0 - k1v * (1.f / 3.f) + k2v;
                else               ec = h0 + k1v - k2v + k3v;
                float kv = __fdividef(sig * th - ec, den[r]);
                if (stg == 0)      { kk1[r] = (_Float16)kv; en[r] = h0 + kv * (1.f / 3.f); }
                else if (stg == 1) { kk2[r] = (_Float16)kv; en[r] = h0 - k1v * (1.f / 3.f) + kv; }
                else if (stg == 2) { kk3[r] = (_Float16)kv; en[r] = h0 + k1v - k2v + kv; }
                else               { en[r] = h0 + 0.125f * (k1v + 3.f * (k2v + k3v) + kv); hv[r] = en[r]; }
            }
            if (lane < 16) { wbuf[0][u] = f2bf(en[0]); wbuf[1][u] = f2bf(en[1]); }

            __syncthreads();   // write-buffer visible; read-buffer never written
        }
    }

    // ---- epilogue: out = h @ W_fc^T + b_fc ----
    if (lane < 16) { hout[0][u] = hv[0]; hout[1][u] = hv[1]; }
    __syncthreads();
    if (tid < 20) {
        int r = tid / 10, c = tid % 10;
        float acc = b_fc[c];
        for (int k = 0; k < 256; ++k) acc = fmaf(hout[r][k], W_fc[c * 256 + k], acc);
        out[(row0 + r) * 10 + c] = acc;
    }
}

extern "C" void kernel_launch(void* const* d_in, const int* in_sizes, int n_in,
                              void* d_out, int out_size, void* d_ws, size_t ws_size,
                              hipStream_t stream) {
    (void)in_sizes; (void)n_in; (void)out_size; (void)ws_size;
    unsigned short* ws16 = (unsigned short*)d_ws;
    prepack_kernel<<<256, 256, 0, stream>>>((const float*)d_in[1], ws16);
    ltc_kernel<<<256, 1024, 0, stream>>>(
        (const float*)d_in[0], (const float*)d_in[1], (const float*)d_in[2],
        (const float*)d_in[3], (const float*)d_in[4], (const float*)d_in[5],
        (const float*)d_in[6], (const float*)d_in[7], (const float*)d_in[8],
        ws16, (float*)d_out);
}